// Round 10
// baseline (241.053 us; speedup 1.0000x reference)
//
#include <hip/hip_runtime.h>
#include <cstdint>
#include <cstddef>

// Problem constants (fixed by reference)
constexpr int B_ = 8, N_ = 4096, C_ = 256, H_ = 4, D_ = 64, P_ = 64;
constexpr int OC_ = 4 * C_;      // 1024 qkvv channels
constexpr int M_  = B_ * N_;     // 32768 tokens
constexpr int GX_ROWS = 320;     // 256 G rows + 64 xEt rows (per batch)
constexpr int KS_G = 8;          // token K-splits for gram partials
constexpr int XT_TILES = M_ / 64;  // 512 transpose tiles

#define DEV_INLINE __device__ __forceinline__

typedef unsigned short ushort_t;
typedef __attribute__((ext_vector_type(8))) short short8;    // 8 bf16 = 4 VGPR
typedef __attribute__((ext_vector_type(4))) short short4v;   // 4 bf16 = 8 B
typedef __attribute__((ext_vector_type(4))) float floatx4;   // MFMA acc

DEV_INLINE short f2bf(float f) {  // RNE f32 -> bf16
  unsigned int u = __builtin_bit_cast(unsigned int, f);
  u += 0x7FFFu + ((u >> 16) & 1u);
  return (short)(u >> 16);
}
DEV_INLINE float bf2f(ushort_t u) {
  return __builtin_bit_cast(float, (unsigned int)u << 16);
}
DEV_INLINE short4v cvt4(float4 v) {
  short4v s = {f2bf(v.x), f2bf(v.y), f2bf(v.z), f2bf(v.w)};
  return s;
}

// ---------------------------------------------------------------------------
// k_cast:
//   block 0 additionally zeroes ssq (replaces hipMemsetAsync).
//   blocks < XT_TILES: cast one 64-token x-tile, write transpose into xt.
//   blocks < XT_TILES+128: cast weights f32->bf16.
//   blocks < XT_TILES+136: transpose Wq q-rows (0..255) -> wqtq[c][d],
//                          Wv2 rows (512..767) -> wv2t[c][e].
__global__ __launch_bounds__(256) void k_cast(const float* __restrict__ x,
                                              const float* __restrict__ Wq,
                                              const float* __restrict__ WE,
                                              const float* __restrict__ W1,
                                              const float* __restrict__ W2,
                                              ushort_t* __restrict__ xt,
                                              ushort_t* __restrict__ wqb,
                                              ushort_t* __restrict__ web,
                                              ushort_t* __restrict__ w1b,
                                              ushort_t* __restrict__ w2b,
                                              ushort_t* __restrict__ wqtq,
                                              ushort_t* __restrict__ wv2t,
                                              float* __restrict__ ssq) {
  __shared__ __align__(16) short Xs[64 * 264];   // pad 264 shorts/row
  const int t = threadIdx.x;
  if (blockIdx.x == 0) {  // zero ssq (16 KB) — completes before k_mid1 launches
    for (int i = t; i < B_ * 512; i += 256) ssq[i] = 0.f;
  }
  if (blockIdx.x >= XT_TILES + 128) {  // ---- Wq / Wv2 transpose tiles
    const int tb = blockIdx.x - (XT_TILES + 128);   // 0..7
    const int srcbase = (tb < 4 ? 0 : 512) + (tb & 3) * 64;
    ushort_t* dstm = (tb < 4) ? wqtq : wv2t;
    const int R = (tb & 3) * 64;
#pragma unroll
    for (int rep = 0; rep < 16; ++rep) {
      const int f4 = rep * 256 + t;
      const int row = f4 >> 6, c4 = f4 & 63;
      float4 v = *(const float4*)&Wq[(size_t)(srcbase + row) * 256 + c4 * 4];
      *(short4v*)&Xs[row * 264 + c4 * 4] = cvt4(v);
    }
    __syncthreads();
    const int ch = t;                       // channel c
    ushort_t* dst = &dstm[ch * 256 + R];
#pragma unroll
    for (int g = 0; g < 8; ++g) {
      short8 o;
#pragma unroll
      for (int i = 0; i < 8; ++i) o[i] = Xs[(g * 8 + i) * 264 + ch];
      *(short8*)&dst[g * 8] = o;
    }
    return;
  }
  if (blockIdx.x >= XT_TILES) {  // ---- weight cast
    constexpr size_t WQ4 = (size_t)OC_ * C_ / 4;   // 65,536 float4
    constexpr size_t WE4 = (size_t)P_ * N_ / 4;    // 65,536
    constexpr size_t W14 = (size_t)128 * C_ / 4;   //  8,192
    constexpr size_t TOTW4 = WQ4 + WE4 + 2 * W14;
    const size_t stride = (size_t)128 * 256;
    for (size_t i = (size_t)(blockIdx.x - XT_TILES) * 256 + t; i < TOTW4; i += stride) {
      const float* src; ushort_t* dst; size_t o;
      if (i < WQ4) { src = Wq; dst = wqb; o = i; }
      else if (i < WQ4 + WE4) { src = WE; dst = web; o = i - WQ4; }
      else if (i < WQ4 + WE4 + W14) { src = W1; dst = w1b; o = i - WQ4 - WE4; }
      else { src = W2; dst = w2b; o = i - WQ4 - WE4 - W14; }
      float4 v = ((const float4*)src)[o];
      *(short4v*)&dst[o * 4] = cvt4(v);
    }
    return;
  }
  // ---- x tile: 64 tokens x 256 channels -> transposed bf16
  const int n0 = blockIdx.x * 64;                // global token base
  const int b = n0 >> 12, nl = n0 & 4095;
#pragma unroll
  for (int rep = 0; rep < 16; ++rep) {
    const int f4 = rep * 256 + t;                // 0..4095 float4 of tile
    const int row = f4 >> 6, c4 = f4 & 63;
    float4 v = *(const float4*)&x[(size_t)(n0 + row) * 256 + c4 * 4];
    *(short4v*)&Xs[row * 264 + c4 * 4] = cvt4(v);
  }
  __syncthreads();
  const int ch = t;
  ushort_t* dst = &xt[((size_t)b * 256 + ch) * 4096 + nl];
#pragma unroll
  for (int g = 0; g < 8; ++g) {
    short8 o;
#pragma unroll
    for (int i = 0; i < 8; ++i) o[i] = Xs[(g * 8 + i) * 264 + ch];
    *(short8*)&dst[g * 8] = o;
  }
}

// ---------------------------------------------------------------------------
// k_gram v3: natural-layout GEMM from xt. Per (job, b, ksp) block:
//   job 0/1: rows = xt channels job*128..+127; job 2: rows = WE rows 0..63.
__global__ __launch_bounds__(512) void k_gram(const ushort_t* __restrict__ xt,
                                              const ushort_t* __restrict__ web,
                                              float* __restrict__ Gxp) {
  __shared__ __align__(16) short As[128 * 72];
  __shared__ __align__(16) short Bs[256 * 72];
  const int job = blockIdx.x;
  const int y = blockIdx.y;            // b*8 + ksp
  const int b = y >> 3, ksp = y & 7;
  const int t = threadIdx.x;
  const int oc = t & 7, rr = t >> 3;
  const int lane = t & 63, wave = t >> 6;
  const int m16 = lane & 15, quad = lane >> 4;
  const int wm = (wave >> 2) << 6, wn = (wave & 3) << 6;
  const ushort_t* Asrc = (job < 2)
      ? xt + (size_t)(b * 256 + job * 128) * 4096 : web;
  const ushort_t* Bsrc = xt + (size_t)b * 256 * 4096;
  floatx4 acc[4][4];
#pragma unroll
  for (int i = 0; i < 4; ++i)
#pragma unroll
    for (int j = 0; j < 4; ++j) acc[i][j] = (floatx4)(0.f);
#pragma unroll 1
  for (int it = 0; it < 8; ++it) {
    const int n0 = ksp * 512 + it * 64;
    short8 a8[2], b8[4];
#pragma unroll
    for (int rp = 0; rp < 2; ++rp) {
      int ar = rr + 64 * rp;
      if (job == 2) ar &= 63;          // WE has 64 rows; dup into pad region
      a8[rp] = *(const short8*)&Asrc[(size_t)ar * 4096 + n0 + 8 * oc];
    }
#pragma unroll
    for (int rp = 0; rp < 4; ++rp)
      b8[rp] = *(const short8*)&Bsrc[(size_t)(rr + 64 * rp) * 4096 + n0 + 8 * oc];
    __syncthreads();
#pragma unroll
    for (int rp = 0; rp < 2; ++rp)
      *(short8*)&As[(rr + 64 * rp) * 72 + 8 * oc] = a8[rp];
#pragma unroll
    for (int rp = 0; rp < 4; ++rp)
      *(short8*)&Bs[(rr + 64 * rp) * 72 + 8 * oc] = b8[rp];
    __syncthreads();
#pragma unroll
    for (int ks = 0; ks < 2; ++ks) {
      if (job < 2) {
        short8 af[4], bf[4];
#pragma unroll
        for (int i = 0; i < 4; ++i)
          af[i] = *(const short8*)&As[(wm + i * 16 + m16) * 72 + ks * 32 + quad * 8];
#pragma unroll
        for (int j = 0; j < 4; ++j)
          bf[j] = *(const short8*)&Bs[(wn + j * 16 + m16) * 72 + ks * 32 + quad * 8];
#pragma unroll
        for (int i = 0; i < 4; ++i)
#pragma unroll
          for (int j = 0; j < 4; ++j)
            acc[i][j] = __builtin_amdgcn_mfma_f32_16x16x32_bf16(af[i], bf[j], acc[i][j], 0, 0, 0);
      } else {  // 64 A-rows, 8 waves each own a 64x32 col strip
        short8 af[4], bf[2];
#pragma unroll
        for (int i = 0; i < 4; ++i)
          af[i] = *(const short8*)&As[(i * 16 + m16) * 72 + ks * 32 + quad * 8];
#pragma unroll
        for (int j = 0; j < 2; ++j)
          bf[j] = *(const short8*)&Bs[(wave * 32 + j * 16 + m16) * 72 + ks * 32 + quad * 8];
#pragma unroll
        for (int i = 0; i < 4; ++i)
#pragma unroll
          for (int j = 0; j < 2; ++j)
            acc[i][j] = __builtin_amdgcn_mfma_f32_16x16x32_bf16(af[i], bf[j], acc[i][j], 0, 0, 0);
      }
    }
  }
  float* pb = Gxp + (size_t)y * (GX_ROWS * 256);
  if (job < 2) {
#pragma unroll
    for (int i = 0; i < 4; ++i)
#pragma unroll
      for (int r = 0; r < 4; ++r) {
        const int grow = job * 128 + wm + i * 16 + quad * 4 + r;
#pragma unroll
        for (int j = 0; j < 4; ++j)
          pb[(size_t)grow * 256 + wn + j * 16 + m16] = acc[i][j][r];
      }
  } else {
#pragma unroll
    for (int i = 0; i < 4; ++i)
#pragma unroll
      for (int r = 0; r < 4; ++r) {
        const int grow = 256 + i * 16 + quad * 4 + r;
#pragma unroll
        for (int j = 0; j < 2; ++j)
          pb[(size_t)grow * 256 + wave * 32 + j * 16 + m16] = acc[i][j][r];
      }
  }
}

// Reduce KS_G partials -> Gx. 163,840 float4.
__global__ __launch_bounds__(256) void k_gred(const float* __restrict__ Gxp,
                                              float* __restrict__ Gx) {
  const int i = blockIdx.x * 256 + threadIdx.x;   // float4 index
  constexpr int PB4 = GX_ROWS * 256 / 4;          // 20,480 float4 per partial
  const int fb = i / PB4, rem = i - fb * PB4;
  const float4* p = (const float4*)Gxp;
  float4 s = p[(size_t)fb * KS_G * PB4 + rem];
#pragma unroll
  for (int k = 1; k < KS_G; ++k) {
    float4 v = p[((size_t)fb * KS_G + k) * PB4 + rem];
    s.x += v.x; s.y += v.y; s.z += v.z; s.w += v.w;
  }
  ((float4*)Gx)[i] = s;
}

// ---------------------------------------------------------------------------
// k_mid1: T2 = W[0:512] @ G_b -> bf16 T2b, fused ssq diag quad-form atomics.
__global__ __launch_bounds__(256) void k_mid1(const ushort_t* __restrict__ wqb,
                                              const float* __restrict__ Gx,
                                              ushort_t* __restrict__ T2b,
                                              float* __restrict__ ssq) {
  __shared__ __align__(16) short As[128 * 72];
  __shared__ __align__(16) short Bs[128 * 72];
  const int bm = blockIdx.x * 128;     // W rows 0..511
  const int b  = blockIdx.y >> 1;
  const int jb = blockIdx.y & 1;       // G col block
  const int t = threadIdx.x;
  const int oc = t & 7;
  const int rr = t >> 3;
  const int lane = t & 63, wave = t >> 6;
  const int m16 = lane & 15, quad = lane >> 4;
  const int wm = (wave >> 1) << 6, wn = (wave & 1) << 6;
  const float* Bsrc = Gx + ((size_t)b * GX_ROWS + jb * 128) * 256;
  floatx4 acc[4][4];
#pragma unroll
  for (int i = 0; i < 4; ++i)
#pragma unroll
    for (int j = 0; j < 4; ++j) acc[i][j] = (floatx4)(0.f);
#pragma unroll 1
  for (int k0 = 0; k0 < 256; k0 += 64) {
    short8 a8[4], b8[4];
#pragma unroll
    for (int j = 0; j < 4; ++j) {
      const int r = rr + 32 * j;
      a8[j] = *(const short8*)&wqb[(size_t)(bm + r) * 256 + k0 + 8 * oc];
      float4 g0 = *(const float4*)&Bsrc[(size_t)r * 256 + k0 + 8 * oc];
      float4 g1 = *(const float4*)&Bsrc[(size_t)r * 256 + k0 + 8 * oc + 4];
      short8 bb;
      bb[0] = f2bf(g0.x); bb[1] = f2bf(g0.y); bb[2] = f2bf(g0.z); bb[3] = f2bf(g0.w);
      bb[4] = f2bf(g1.x); bb[5] = f2bf(g1.y); bb[6] = f2bf(g1.z); bb[7] = f2bf(g1.w);
      b8[j] = bb;
    }
    __syncthreads();
#pragma unroll
    for (int j = 0; j < 4; ++j) {
      const int r = rr + 32 * j;
      *(short8*)&As[r * 72 + 8 * oc] = a8[j];
      *(short8*)&Bs[r * 72 + 8 * oc] = b8[j];
    }
    __syncthreads();
#pragma unroll
    for (int ks = 0; ks < 2; ++ks) {
      short8 af[4], bf[4];
#pragma unroll
      for (int i = 0; i < 4; ++i)
        af[i] = *(const short8*)&As[(wm + i * 16 + m16) * 72 + ks * 32 + quad * 8];
#pragma unroll
      for (int j = 0; j < 4; ++j)
        bf[j] = *(const short8*)&Bs[(wn + j * 16 + m16) * 72 + ks * 32 + quad * 8];
#pragma unroll
      for (int i = 0; i < 4; ++i)
#pragma unroll
        for (int j = 0; j < 4; ++j)
          acc[i][j] = __builtin_amdgcn_mfma_f32_16x16x32_bf16(af[i], bf[j], acc[i][j], 0, 0, 0);
    }
  }
#pragma unroll
  for (int i = 0; i < 4; ++i)
#pragma unroll
    for (int r = 0; r < 4; ++r) {
      const int gr = bm + wm + i * 16 + quad * 4 + r;  // 0..511
      float s = 0.f;
#pragma unroll
      for (int j = 0; j < 4; ++j) {
        const int col = jb * 128 + wn + j * 16 + m16;
        T2b[((size_t)b * 512 + gr) * 256 + col] = (ushort_t)f2bf(acc[i][j][r]);
        s += bf2f(wqb[(size_t)gr * 256 + col]) * acc[i][j][r];
      }
      s += __shfl_xor(s, 1);
      s += __shfl_xor(s, 2);
      s += __shfl_xor(s, 4);
      s += __shfl_xor(s, 8);
      if (m16 == 0) atomicAdd(&ssq[b * 512 + gr], s);
    }
}

// ---------------------------------------------------------------------------
// k_mid2 (fused mid2+mid3): one block per bh, 4 waves (wave = 16-row slice /
// c-64-block). Phase 1: three 64x64 K=256 GEMMs (ab->LDS, ksb->LDS, vsb->glob).
// Phase 2 (after barrier): Kc = Kb @ wqtq_h^T, AcT = Ab @ wv2t_h^T.
__global__ __launch_bounds__(256) void k_mid2(const ushort_t* __restrict__ wqb,
                                              const ushort_t* __restrict__ T2b,
                                              const float* __restrict__ Gx,
                                              const float* __restrict__ ssq,
                                              const float* __restrict__ bE,
                                              const float* __restrict__ t1,
                                              const float* __restrict__ t2,
                                              const ushort_t* __restrict__ wqtq,
                                              const ushort_t* __restrict__ wv2t,
                                              ushort_t* __restrict__ vsb,
                                              ushort_t* __restrict__ Kc,
                                              ushort_t* __restrict__ AcT) {
  __shared__ __align__(16) short Ab[64 * 64];   // ab  [dd][e]
  __shared__ __align__(16) short Kb[64 * 64];   // ksb [p][d]
  const int bh = blockIdx.x;
  const int b = bh >> 2, h = bh & 3;
  const int wave = threadIdx.x >> 6;
  const int lane = threadIdx.x & 63;
  const int m16 = lane & 15, quad = lane >> 4;
  // ---- job 0: channel-attn logits + softmax -> Ab (LDS)
  {
    const int arow = h * 64 + 16 * wave + m16;
    floatx4 acc[4];
#pragma unroll
    for (int j = 0; j < 4; ++j) acc[j] = (floatx4)(0.f);
#pragma unroll
    for (int ks = 0; ks < 8; ++ks) {
      const int boct = ks * 32 + quad * 8;
      short8 af = *(const short8*)&wqb[(size_t)arow * 256 + boct];
      short8 bf[4];
#pragma unroll
      for (int j = 0; j < 4; ++j)
        bf[j] = *(const short8*)&T2b[((size_t)b * 512 + 256 + h * 64 + 16 * j + m16) * 256 + boct];
#pragma unroll
      for (int j = 0; j < 4; ++j)
        acc[j] = __builtin_amdgcn_mfma_f32_16x16x32_bf16(af, bf[j], acc[j], 0, 0, 0);
    }
    const float t1h = t1[h];
    float rnk[4];
#pragma unroll
    for (int j = 0; j < 4; ++j)
      rnk[j] = 1.f / fmaxf(sqrtf(ssq[b * 512 + 256 + h * 64 + 16 * j + m16]), 1e-12f);
#pragma unroll
    for (int r = 0; r < 4; ++r) {
      const int d = 16 * wave + quad * 4 + r;
      const float rq = 1.f / fmaxf(sqrtf(ssq[b * 512 + h * 64 + d]), 1e-12f);
      float l[4];
      float m = -1e30f;
#pragma unroll
      for (int j = 0; j < 4; ++j) {
        l[j] = acc[j][r] * rq * rnk[j] * t1h;
        m = fmaxf(m, l[j]);
      }
      m = fmaxf(m, __shfl_xor(m, 1));
      m = fmaxf(m, __shfl_xor(m, 2));
      m = fmaxf(m, __shfl_xor(m, 4));
      m = fmaxf(m, __shfl_xor(m, 8));
      float s = 0.f;
#pragma unroll
      for (int j = 0; j < 4; ++j) {
        l[j] = __expf(l[j] - m);
        s += l[j];
      }
      s += __shfl_xor(s, 1);
      s += __shfl_xor(s, 2);
      s += __shfl_xor(s, 4);
      s += __shfl_xor(s, 8);
      const float inv = 1.f / s;
#pragma unroll
      for (int j = 0; j < 4; ++j)
        Ab[d * 64 + 16 * j + m16] = (short)f2bf(l[j] * inv);
    }
  }
  // ---- job 1: ksb -> Kb (LDS, [p][d])
  {
    const int arow = 256 + h * 64 + 16 * wave + m16;
    floatx4 acc[4];
#pragma unroll
    for (int j = 0; j < 4; ++j) acc[j] = (floatx4)(0.f);
#pragma unroll
    for (int ks = 0; ks < 8; ++ks) {
      const int boct = ks * 32 + quad * 8;
      short8 af = *(const short8*)&wqb[(size_t)arow * 256 + boct];
      short8 bf[4];
#pragma unroll
      for (int j = 0; j < 4; ++j) {
        const float* gp = Gx + ((size_t)b * GX_ROWS + 256 + 16 * j + m16) * 256 + boct;
        float4 g0 = *(const float4*)gp;
        float4 g1 = *(const float4*)(gp + 4);
        short8 bb;
        bb[0] = f2bf(g0.x); bb[1] = f2bf(g0.y); bb[2] = f2bf(g0.z); bb[3] = f2bf(g0.w);
        bb[4] = f2bf(g1.x); bb[5] = f2bf(g1.y); bb[6] = f2bf(g1.z); bb[7] = f2bf(g1.w);
        bf[j] = bb;
      }
#pragma unroll
      for (int j = 0; j < 4; ++j)
        acc[j] = __builtin_amdgcn_mfma_f32_16x16x32_bf16(af, bf[j], acc[j], 0, 0, 0);
    }
    const float tt = t2[h];
#pragma unroll
    for (int r = 0; r < 4; ++r) {
      const int d = 16 * wave + quad * 4 + r;
      const float rq = 1.f / fmaxf(sqrtf(ssq[b * 512 + h * 64 + d]), 1e-12f);
#pragma unroll
      for (int j = 0; j < 4; ++j) {
        const int p = 16 * j + m16;
        Kb[p * 64 + d] = (short)f2bf((acc[j][r] + bE[p]) * rq * tt);
      }
    }
  }
  // ---- job 2: vsb -> global
  {
    const int arow = 768 + h * 64 + 16 * wave + m16;
    floatx4 acc[4];
#pragma unroll
    for (int j = 0; j < 4; ++j) acc[j] = (floatx4)(0.f);
#pragma unroll
    for (int ks = 0; ks < 8; ++ks) {
      const int boct = ks * 32 + quad * 8;
      short8 af = *(const short8*)&wqb[(size_t)arow * 256 + boct];
      short8 bf[4];
#pragma unroll
      for (int j = 0; j < 4; ++j) {
        const float* gp = Gx + ((size_t)b * GX_ROWS + 256 + 16 * j + m16) * 256 + boct;
        float4 g0 = *(const float4*)gp;
        float4 g1 = *(const float4*)(gp + 4);
        short8 bb;
        bb[0] = f2bf(g0.x); bb[1] = f2bf(g0.y); bb[2] = f2bf(g0.z); bb[3] = f2bf(g0.w);
        bb[4] = f2bf(g1.x); bb[5] = f2bf(g1.y); bb[6] = f2bf(g1.z); bb[7] = f2bf(g1.w);
        bf[j] = bb;
      }
#pragma unroll
      for (int j = 0; j < 4; ++j)
        acc[j] = __builtin_amdgcn_mfma_f32_16x16x32_bf16(af, bf[j], acc[j], 0, 0, 0);
    }
#pragma unroll
    for (int r = 0; r < 4; ++r) {
      const int d = 16 * wave + quad * 4 + r;
#pragma unroll
      for (int j = 0; j < 4; ++j) {
        const int p = 16 * j + m16;
        vsb[(size_t)bh * 4096 + d * 64 + p] = (ushort_t)f2bf(acc[j][r] + bE[p]);
      }
    }
  }
  __syncthreads();
  // ---- phase 2a: Kc[p][c] = sum_d Kb[p][d] * wqtq[c][h*64+d]; wave = c-block
  {
    floatx4 acc[4][4];
#pragma unroll
    for (int i = 0; i < 4; ++i)
#pragma unroll
      for (int j = 0; j < 4; ++j) acc[i][j] = (floatx4)(0.f);
#pragma unroll
    for (int ks = 0; ks < 2; ++ks) {
      const int boct = ks * 32 + quad * 8;
      short8 af[4], bf[4];
#pragma unroll
      for (int i = 0; i < 4; ++i)
        af[i] = *(const short8*)&Kb[(16 * i + m16) * 64 + boct];
#pragma unroll
      for (int j = 0; j < 4; ++j)
        bf[j] = *(const short8*)&wqtq[(size_t)(wave * 64 + 16 * j + m16) * 256 + h * 64 + boct];
#pragma unroll
      for (int i = 0; i < 4; ++i)
#pragma unroll
        for (int j = 0; j < 4; ++j)
          acc[i][j] = __builtin_amdgcn_mfma_f32_16x16x32_bf16(af[i], bf[j], acc[i][j], 0, 0, 0);
    }
#pragma unroll
    for (int i = 0; i < 4; ++i)
#pragma unroll
      for (int r = 0; r < 4; ++r) {
        const int p = 16 * i + quad * 4 + r;
#pragma unroll
        for (int j = 0; j < 4; ++j) {
          const int cc = wave * 64 + 16 * j + m16;
          Kc[(size_t)bh * 16384 + p * 256 + cc] = (ushort_t)f2bf(acc[i][j][r]);
        }
      }
  }
  // ---- phase 2b: AcT[c][dd] = sum_e Ab[dd][e] * wv2t[c][h*64+e]
  {
    floatx4 acc[4][4];
#pragma unroll
    for (int i = 0; i < 4; ++i)
#pragma unroll
      for (int j = 0; j < 4; ++j) acc[i][j] = (floatx4)(0.f);
#pragma unroll
    for (int ks = 0; ks < 2; ++ks) {
      const int boct = ks * 32 + quad * 8;
      short8 af[4], bf[4];
#pragma unroll
      for (int i = 0; i < 4; ++i)
        af[i] = *(const short8*)&Ab[(16 * i + m16) * 64 + boct];
#pragma unroll
      for (int j = 0; j < 4; ++j)
        bf[j] = *(const short8*)&wv2t[(size_t)(wave * 64 + 16 * j + m16) * 256 + h * 64 + boct];
#pragma unroll
      for (int i = 0; i < 4; ++i)
#pragma unroll
        for (int j = 0; j < 4; ++j)
          acc[i][j] = __builtin_amdgcn_mfma_f32_16x16x32_bf16(af[i], bf[j], acc[i][j], 0, 0, 0);
    }
#pragma unroll
    for (int i = 0; i < 4; ++i)
#pragma unroll
      for (int r = 0; r < 4; ++r) {
        const int dd = 16 * i + quad * 4 + r;
#pragma unroll
        for (int j = 0; j < 4; ++j) {
          const int cc = wave * 64 + 16 * j + m16;
          AcT[(size_t)bh * 16384 + cc * 64 + dd] = (ushort_t)f2bf(acc[i][j][r]);
        }
      }
  }
}

// ---------------------------------------------------------------------------
// k_mid4: M2[b][o][c] = sum_{m=h*64+dd} W2[o,m] * AcT[b4+h][c][dd].
// Grid (8, 2): block = 64 o-rows x 256 c. wave = c-64-block. K=256.
__global__ __launch_bounds__(256) void k_mid4(const ushort_t* __restrict__ w2b,
                                              const ushort_t* __restrict__ AcT,
                                              ushort_t* __restrict__ M2) {
  const int b = blockIdx.x;
  const int ob = blockIdx.y * 64;
  const int wave = threadIdx.x >> 6;   // c block
  const int lane = threadIdx.x & 63;
  const int m16 = lane & 15, quad = lane >> 4;
  floatx4 acc[4][4];
#pragma unroll
  for (int i = 0; i < 4; ++i)
#pragma unroll
    for (int j = 0; j < 4; ++j) acc[i][j] = (floatx4)(0.f);
#pragma unroll
  for (int ks = 0; ks < 8; ++ks) {
    const int boct = ks * 32 + quad * 8;
    const int hsel = boct >> 6, de = boct & 63;
    short8 af[4], bf[4];
#pragma unroll
    for (int i = 0; i < 4; ++i)
      af[i] = *(const short8*)&w2b[(size_t)(ob + 16 * i + m16) * 256 + boct];
#pragma unroll
    for (int j = 0; j < 4; ++j)
      bf[j] = *(const short8*)&AcT[((size_t)(b * 4 + hsel)) * 16384 +
                                   (wave * 64 + 16 * j + m16) * 64 + de];
#pragma unroll
    for (int i = 0; i < 4; ++i)
#pragma unroll
      for (int j = 0; j < 4; ++j)
        acc[i][j] = __builtin_amdgcn_mfma_f32_16x16x32_bf16(af[i], bf[j], acc[i][j], 0, 0, 0);
  }
#pragma unroll
  for (int i = 0; i < 4; ++i)
#pragma unroll
    for (int r = 0; r < 4; ++r) {
      const int oo = ob + 16 * i + quad * 4 + r;
#pragma unroll
      for (int j = 0; j < 4; ++j)
        M2[(size_t)b * 32768 + oo * 256 + wave * 64 + 16 * j + m16] =
            (ushort_t)f2bf(acc[i][j][r]);
    }
}

// ---------------------------------------------------------------------------
// k_tok v2: one block = 64 tokens, 4 waves (wave = head). Phases:
//  1: stage x -> Xs (read-only afterwards).
//  A: S = x @ Kc_h^T (K=256) -> softmax -> P -> Ys strip.
//  B: x_sa = P @ vsb^T -> Ys strip.  [barrier]
//  C: waves 0,1: out_sa = x_sa @ W1^T; waves 2,3: out_ca = x @ M2_b^T.
__global__ __launch_bounds__(256, 2) void k_tok(const float* __restrict__ x,
                                                const ushort_t* __restrict__ Kc,
                                                const ushort_t* __restrict__ vsb,
                                                const ushort_t* __restrict__ M2,
                                                const ushort_t* __restrict__ w1b,
                                                const float* __restrict__ b1,
                                                const float* __restrict__ b2,
                                                const float* __restrict__ pa,
                                                float* __restrict__ out) {
  __shared__ __align__(16) short Xs[64 * 264];
  __shared__ __align__(16) short Ys[64 * 264];
  const int n0 = blockIdx.x * 64;
  const int b = n0 >> 12;
  const int t = threadIdx.x;
  const int lane = t & 63, wave = t >> 6;
  const int m16 = lane & 15, quad = lane >> 4;
  const int cw = wave * 64;            // this wave's column strip / head base
  const int bh = b * 4 + wave;
  // ---- phase 1: stage x tile (f32 -> bf16)
#pragma unroll
  for (int rep = 0; rep < 16; ++rep) {
    const int f4 = rep * 256 + t;
    const int row = f4 >> 6, c4 = f4 & 63;
    float4 v = *(const float4*)&x[(size_t)(n0 + row) * 256 + c4 * 4];
    *(short4v*)&Xs[row * 264 + c4 * 4] = cvt4(v);
  }
  __syncthreads();
  // ---- phase A: S = x @ Kc_h^T (K=256), softmax, P -> Ys strip
  {
    floatx4 s[4][4];
#pragma unroll
    for (int i = 0; i < 4; ++i)
#pragma unroll
      for (int j = 0; j < 4; ++j) s[i][j] = (floatx4)(0.f);
#pragma unroll
    for (int ks = 0; ks < 8; ++ks) {
      const int boct = ks * 32 + quad * 8;
      short8 af[4], bf[4];
#pragma unroll
      for (int i = 0; i < 4; ++i)
        af[i] = *(const short8*)&Xs[(16 * i + m16) * 264 + boct];
#pragma unroll
      for (int j = 0; j < 4; ++j)
        bf[j] = *(const short8*)&Kc[(size_t)bh * 16384 + (16 * j + m16) * 256 + boct];
#pragma unroll
      for (int i = 0; i < 4; ++i)
#pragma unroll
        for (int j = 0; j < 4; ++j)
          s[i][j] = __builtin_amdgcn_mfma_f32_16x16x32_bf16(af[i], bf[j], s[i][j], 0, 0, 0);
    }
    // softmax per token-row (64 wide: 4 j-blocks x 16 lanes)
#pragma unroll
    for (int i = 0; i < 4; ++i)
#pragma unroll
      for (int r = 0; r < 4; ++r) {
        float mr = fmaxf(fmaxf(s[i][0][r], s[i][1][r]), fmaxf(s[i][2][r], s[i][3][r]));
        mr = fmaxf(mr, __shfl_xor(mr, 1));
        mr = fmaxf(mr, __shfl_xor(mr, 2));
        mr = fmaxf(mr, __shfl_xor(mr, 4));
        mr = fmaxf(mr, __shfl_xor(mr, 8));
        float sr = 0.f;
#pragma unroll
        for (int j = 0; j < 4; ++j) {
          const float e = __expf(s[i][j][r] - mr);
          s[i][j][r] = e;
          sr += e;
        }
        sr += __shfl_xor(sr, 1);
        sr += __shfl_xor(sr, 2);
        sr += __shfl_xor(sr, 4);
        sr += __shfl_xor(sr, 8);
        const float inv = 1.f / sr;
#pragma unroll
        for (int j = 0; j < 4; ++j) s[i][j][r] *= inv;
      }
    // P -> Ys strip
#pragma unroll
    for (int i = 0; i < 4; ++i)
#pragma unroll
      for (int r = 0; r < 4; ++r)
#pragma unroll
        for (int j = 0; j < 4; ++j)
          Ys[(16 * i + quad * 4 + r) * 264 + cw + 16 * j + m16] =
              (short)f2bf(s[i][j][r]);
  }
  // ---- phase B: x_sa = P @ vsb^T -> Ys strip (intra-wave LDS dependence)
  {
    floatx4 o[4][4];
#pragma unroll
    for (int i = 0; i < 4; ++i)
#pragma unroll
      for (int j = 0; j < 4; ++j) o[i][j] = (floatx4)(0.f);
#pragma unroll
    for (int ks = 0; ks < 2; ++ks) {
      const int boct = ks * 32 + quad * 8;
      short8 af[4], bf[4];
#pragma unroll
      for (int i = 0; i < 4; ++i)
        af[i] = *(const short8*)&Ys[(16 * i + m16) * 264 + cw + boct];
#pragma unroll
      for (int j = 0; j < 4; ++j)
        bf[j] = *(const short8*)&vsb[(size_t)bh * 4096 + (16 * j + m16) * 64 + boct];
#pragma unroll
      for (int i = 0; i < 4; ++i)
#pragma unroll
        for (int j = 0; j < 4; ++j)
          o[i][j] = __builtin_amdgcn_mfma_f32_16x16x32_bf16(af[i], bf[j], o[i][j], 0, 0, 0);
    }
#pragma unroll
    for (int i = 0; i < 4; ++i)
#pragma unroll
      for (int r = 0; r < 4; ++r)
#pragma unroll
        for (int j = 0; j < 4; ++j)
          Ys[(16 * i + quad * 4 + r) * 264 + cw + 16 * j + m16] =
              (short)f2bf(o[i][j][r]);
  }
  __syncthreads();   // Ys = x_sa complete across waves; Xs still = x
  // ---- phase C: out = PReLU([x_sa@W1^T ; x@M2^T] + bias)
  {
    const short* Asrc = (wave < 2) ? Ys : Xs;
    const ushort_t* Wsrc = (wave < 2) ? w1b : (M2 + (size_t)b * 32768);
    const float* bias = (wave < 2) ? b1 : b2;
    const int wrow = (wave & 1) * 64;
    const int colbase = (wave < 2 ? 0 : 128) + wrow;
    floatx4 acc[4][4];
#pragma unroll
    for (int i = 0; i < 4; ++i)
#pragma unroll
      for (int j = 0; j < 4; ++j) acc[i][j] = (floatx4)(0.f);
#pragma unroll
    for (int ks = 0; ks < 8; ++ks) {
      const int boct = ks * 32 + quad * 8;
      short8 af[4], bf[4];
#pragma unroll
      for (int i = 0; i < 4; ++i)
        af[i] = *(const short8*)&Asrc[(16 * i + m16) * 264 + boct];
#pragma unroll
      for (int j = 0; j < 4; ++j)
        bf[j] = *(const short8*)&Wsrc[(size_t)(wrow + 16 * j + m16) * 256 + boct];
#pragma unroll
      for (int i = 0; i < 4; ++i)
#pragma unroll
        for (int j = 0; j < 4; ++j)
          acc[i][j] = __builtin_amdgcn_mfma_f32_16x16x32_bf16(af[i], bf[j], acc[i][j], 0, 0, 0);
    }
    const float slope = pa[0];
    float bj[4];
#pragma unroll
    for (int j = 0; j < 4; ++j) bj[j] = bias[wrow + 16 * j + m16];
#pragma unroll
    for (int i = 0; i < 4; ++i)
#pragma unroll
      for (int r = 0; r < 4; ++r) {
        const int gr = n0 + 16 * i + quad * 4 + r;
#pragma unroll
        for (int j = 0; j < 4; ++j) {
          float v = acc[i][j][r] + bj[j];
          v = v >= 0.f ? v : slope * v;
          out[(size_t)gr * C_ + colbase + 16 * j + m16] = v;
        }
      }
  }
}

// ---------------------------------------------------------------------------
extern "C" void kernel_launch(void* const* d_in, const int* in_sizes, int n_in,
                              void* d_out, int out_size, void* d_ws, size_t ws_size,
                              hipStream_t stream) {
  (void)in_sizes; (void)n_in; (void)out_size; (void)ws_size;
  const float* x  = (const float*)d_in[0];
  // d_in[1] = bank (unused by forward)
  const float* Wq = (const float*)d_in[2];
  const float* WE = (const float*)d_in[3];
  const float* bE = (const float*)d_in[4];
  const float* t1 = (const float*)d_in[5];
  const float* t2 = (const float*)d_in[6];
  const float* W1 = (const float*)d_in[7];
  const float* b1 = (const float*)d_in[8];
  const float* W2 = (const float*)d_in[9];
  const float* b2 = (const float*)d_in[10];
  const float* pa = (const float*)d_in[11];
  float* out = (float*)d_out;

  float* ws = (float*)d_ws;
  size_t off = 0;
  float* Gx  = ws + off; off += (size_t)B_ * GX_ROWS * 256;          //   655,360
  float* ssq = ws + off; off += (size_t)B_ * 512;                    //     4,096
  float* Gxp = ws + off; off += (size_t)KS_G * B_ * GX_ROWS * 256;   // 5,242,880
  ushort_t* vsb = (ushort_t*)(ws + off); off += 32 * 4096 / 2;  // bf16 [bh][d][p]
  ushort_t* xt  = (ushort_t*)(ws + off); off += (size_t)M_ * C_ / 2;   // bf16 x^T
  ushort_t* wqb = (ushort_t*)(ws + off); off += (size_t)OC_ * C_ / 2;  // bf16 Wq
  ushort_t* w1b = (ushort_t*)(ws + off); off += (size_t)128 * C_ / 2;
  ushort_t* w2b = (ushort_t*)(ws + off); off += (size_t)128 * C_ / 2;
  ushort_t* web = (ushort_t*)(ws + off); off += (size_t)P_ * N_ / 2;   // bf16 WE
  ushort_t* T2b = (ushort_t*)(ws + off); off += (size_t)B_ * 512 * C_ / 2;
  ushort_t* wqtq = (ushort_t*)(ws + off); off += (size_t)256 * 256 / 2; // Wq[0:256]^T
  ushort_t* wv2t = (ushort_t*)(ws + off); off += (size_t)256 * 256 / 2; // Wq[512:768]^T
  ushort_t* Kc  = (ushort_t*)(ws + off); off += (size_t)32 * 16384 / 2; // [bh][p][c]
  ushort_t* AcT = (ushort_t*)(ws + off); off += (size_t)32 * 16384 / 2; // [bh][c][dd]
  ushort_t* M2  = (ushort_t*)(ws + off); off += (size_t)B_ * 32768 / 2; // [b][o][c]

  k_cast<<<XT_TILES + 136, 256, 0, stream>>>(x, Wq, WE, W1, W2,
                                             xt, wqb, web, w1b, w2b, wqtq, wv2t, ssq);
  k_gram<<<dim3(3, B_ * KS_G), 512, 0, stream>>>(xt, web, Gxp);
  k_gred<<<GX_ROWS * 256 * B_ / 4 / 256, 256, 0, stream>>>(Gxp, Gx);
  k_mid1<<<dim3(4, B_ * 2), 256, 0, stream>>>(wqb, Gx, T2b, ssq);
  k_mid2<<<32, 256, 0, stream>>>(wqb, T2b, Gx, ssq, bE, t1, t2,
                                 wqtq, wv2t, vsb, Kc, AcT);
  k_mid4<<<dim3(8, 2), 256, 0, stream>>>(w2b, AcT, M2);
  k_tok<<<M_ / 64, 256, 0, stream>>>(x, Kc, vsb, M2, w1b, b1, b2, pa, out);
}

// Round 11
// 212.006 us; speedup vs baseline: 1.1370x; 1.1370x over previous
//
#include <hip/hip_runtime.h>
#include <cstdint>
#include <cstddef>

// Problem constants (fixed by reference)
constexpr int B_ = 8, N_ = 4096, C_ = 256, H_ = 4, D_ = 64, P_ = 64;
constexpr int OC_ = 4 * C_;      // 1024 qkvv channels
constexpr int M_  = B_ * N_;     // 32768 tokens
constexpr int GX_ROWS = 320;     // 256 G rows + 64 xEt rows (per batch)
constexpr int KS_G = 8;          // token K-splits for gram partials
constexpr int XT_TILES = M_ / 64;  // 512 transpose tiles

#define DEV_INLINE __device__ __forceinline__

typedef unsigned short ushort_t;
typedef __attribute__((ext_vector_type(8))) short short8;    // 8 bf16 = 4 VGPR
typedef __attribute__((ext_vector_type(4))) short short4v;   // 4 bf16 = 8 B
typedef __attribute__((ext_vector_type(4))) float floatx4;   // MFMA acc

DEV_INLINE short f2bf(float f) {  // RNE f32 -> bf16
  unsigned int u = __builtin_bit_cast(unsigned int, f);
  u += 0x7FFFu + ((u >> 16) & 1u);
  return (short)(u >> 16);
}
DEV_INLINE float bf2f(ushort_t u) {
  return __builtin_bit_cast(float, (unsigned int)u << 16);
}
DEV_INLINE short4v cvt4(float4 v) {
  short4v s = {f2bf(v.x), f2bf(v.y), f2bf(v.z), f2bf(v.w)};
  return s;
}

// ---------------------------------------------------------------------------
// k_cast: block 0 additionally zeroes ssq (replaces hipMemsetAsync).
// blocks < XT_TILES: cast one 64-token x-tile and write its transpose
// into xt[b][ch][n] (bf16) via LDS. Blocks >= XT_TILES: cast weights.
__global__ __launch_bounds__(256) void k_cast(const float* __restrict__ x,
                                              const float* __restrict__ Wq,
                                              const float* __restrict__ WE,
                                              const float* __restrict__ W1,
                                              const float* __restrict__ W2,
                                              ushort_t* __restrict__ xt,
                                              ushort_t* __restrict__ wqb,
                                              ushort_t* __restrict__ web,
                                              ushort_t* __restrict__ w1b,
                                              ushort_t* __restrict__ w2b,
                                              float* __restrict__ ssq) {
  const int t = threadIdx.x;
  if (blockIdx.x == 0) {  // zero ssq (16 KB) — done long before k_mid1 runs
    for (int i = t; i < B_ * 512; i += 256) ssq[i] = 0.f;
  }
  if (blockIdx.x >= XT_TILES) {  // ---- weight cast
    constexpr size_t WQ4 = (size_t)OC_ * C_ / 4;   // 65,536 float4
    constexpr size_t WE4 = (size_t)P_ * N_ / 4;    // 65,536
    constexpr size_t W14 = (size_t)128 * C_ / 4;   //  8,192
    constexpr size_t TOTW4 = WQ4 + WE4 + 2 * W14;
    const size_t stride = (size_t)128 * 256;
    for (size_t i = (size_t)(blockIdx.x - XT_TILES) * 256 + t; i < TOTW4; i += stride) {
      const float* src; ushort_t* dst; size_t o;
      if (i < WQ4) { src = Wq; dst = wqb; o = i; }
      else if (i < WQ4 + WE4) { src = WE; dst = web; o = i - WQ4; }
      else if (i < WQ4 + WE4 + W14) { src = W1; dst = w1b; o = i - WQ4 - WE4; }
      else { src = W2; dst = w2b; o = i - WQ4 - WE4 - W14; }
      float4 v = ((const float4*)src)[o];
      *(short4v*)&dst[o * 4] = cvt4(v);
    }
    return;
  }
  // ---- x tile: 64 tokens x 256 channels -> transposed bf16
  __shared__ __align__(16) short Xs[64 * 264];   // pad 264 shorts/row
  const int n0 = blockIdx.x * 64;                // global token base
  const int b = n0 >> 12, nl = n0 & 4095;
#pragma unroll
  for (int rep = 0; rep < 16; ++rep) {
    const int f4 = rep * 256 + t;                // 0..4095 float4 of tile
    const int row = f4 >> 6, c4 = f4 & 63;
    float4 v = *(const float4*)&x[(size_t)(n0 + row) * 256 + c4 * 4];
    *(short4v*)&Xs[row * 264 + c4 * 4] = cvt4(v);
  }
  __syncthreads();
  const int ch = t;
  ushort_t* dst = &xt[((size_t)b * 256 + ch) * 4096 + nl];
#pragma unroll
  for (int g = 0; g < 8; ++g) {
    short8 o;
#pragma unroll
    for (int i = 0; i < 8; ++i) o[i] = Xs[(g * 8 + i) * 264 + ch];
    *(short8*)&dst[g * 8] = o;
  }
}

// ---------------------------------------------------------------------------
// k_gram v3: natural-layout GEMM from xt. Per (job, b, ksp) block:
//   job 0/1: rows = xt channels job*128..+127; job 2: rows = WE rows 0..63.
//   cols    = xt channels 0..255; K = 512-token slice.
__global__ __launch_bounds__(512) void k_gram(const ushort_t* __restrict__ xt,
                                              const ushort_t* __restrict__ web,
                                              float* __restrict__ Gxp) {
  __shared__ __align__(16) short As[128 * 72];
  __shared__ __align__(16) short Bs[256 * 72];
  const int job = blockIdx.x;
  const int y = blockIdx.y;            // b*8 + ksp
  const int b = y >> 3, ksp = y & 7;
  const int t = threadIdx.x;
  const int oc = t & 7, rr = t >> 3;
  const int lane = t & 63, wave = t >> 6;
  const int m16 = lane & 15, quad = lane >> 4;
  const int wm = (wave >> 2) << 6, wn = (wave & 3) << 6;
  const ushort_t* Asrc = (job < 2)
      ? xt + (size_t)(b * 256 + job * 128) * 4096 : web;
  const ushort_t* Bsrc = xt + (size_t)b * 256 * 4096;
  floatx4 acc[4][4];
#pragma unroll
  for (int i = 0; i < 4; ++i)
#pragma unroll
    for (int j = 0; j < 4; ++j) acc[i][j] = (floatx4)(0.f);
#pragma unroll 1
  for (int it = 0; it < 8; ++it) {
    const int n0 = ksp * 512 + it * 64;
    short8 a8[2], b8[4];
#pragma unroll
    for (int rp = 0; rp < 2; ++rp) {
      int ar = rr + 64 * rp;
      if (job == 2) ar &= 63;          // WE has 64 rows; dup into pad region
      a8[rp] = *(const short8*)&Asrc[(size_t)ar * 4096 + n0 + 8 * oc];
    }
#pragma unroll
    for (int rp = 0; rp < 4; ++rp)
      b8[rp] = *(const short8*)&Bsrc[(size_t)(rr + 64 * rp) * 4096 + n0 + 8 * oc];
    __syncthreads();
#pragma unroll
    for (int rp = 0; rp < 2; ++rp)
      *(short8*)&As[(rr + 64 * rp) * 72 + 8 * oc] = a8[rp];
#pragma unroll
    for (int rp = 0; rp < 4; ++rp)
      *(short8*)&Bs[(rr + 64 * rp) * 72 + 8 * oc] = b8[rp];
    __syncthreads();
#pragma unroll
    for (int ks = 0; ks < 2; ++ks) {
      if (job < 2) {
        short8 af[4], bf[4];
#pragma unroll
        for (int i = 0; i < 4; ++i)
          af[i] = *(const short8*)&As[(wm + i * 16 + m16) * 72 + ks * 32 + quad * 8];
#pragma unroll
        for (int j = 0; j < 4; ++j)
          bf[j] = *(const short8*)&Bs[(wn + j * 16 + m16) * 72 + ks * 32 + quad * 8];
#pragma unroll
        for (int i = 0; i < 4; ++i)
#pragma unroll
          for (int j = 0; j < 4; ++j)
            acc[i][j] = __builtin_amdgcn_mfma_f32_16x16x32_bf16(af[i], bf[j], acc[i][j], 0, 0, 0);
      } else {  // 64 A-rows, 8 waves each own a 64x32 col strip
        short8 af[4], bf[2];
#pragma unroll
        for (int i = 0; i < 4; ++i)
          af[i] = *(const short8*)&As[(i * 16 + m16) * 72 + ks * 32 + quad * 8];
#pragma unroll
        for (int j = 0; j < 2; ++j)
          bf[j] = *(const short8*)&Bs[(wave * 32 + j * 16 + m16) * 72 + ks * 32 + quad * 8];
#pragma unroll
        for (int i = 0; i < 4; ++i)
#pragma unroll
          for (int j = 0; j < 2; ++j)
            acc[i][j] = __builtin_amdgcn_mfma_f32_16x16x32_bf16(af[i], bf[j], acc[i][j], 0, 0, 0);
      }
    }
  }
  float* pb = Gxp + (size_t)y * (GX_ROWS * 256);
  if (job < 2) {
#pragma unroll
    for (int i = 0; i < 4; ++i)
#pragma unroll
      for (int r = 0; r < 4; ++r) {
        const int grow = job * 128 + wm + i * 16 + quad * 4 + r;
#pragma unroll
        for (int j = 0; j < 4; ++j)
          pb[(size_t)grow * 256 + wn + j * 16 + m16] = acc[i][j][r];
      }
  } else {
#pragma unroll
    for (int i = 0; i < 4; ++i)
#pragma unroll
      for (int r = 0; r < 4; ++r) {
        const int grow = 256 + i * 16 + quad * 4 + r;
#pragma unroll
        for (int j = 0; j < 2; ++j)
          pb[(size_t)grow * 256 + wave * 32 + j * 16 + m16] = acc[i][j][r];
      }
  }
}

// Reduce KS_G partials -> Gx. 163,840 float4.
__global__ __launch_bounds__(256) void k_gred(const float* __restrict__ Gxp,
                                              float* __restrict__ Gx) {
  const int i = blockIdx.x * 256 + threadIdx.x;   // float4 index
  constexpr int PB4 = GX_ROWS * 256 / 4;          // 20,480 float4 per partial
  const int fb = i / PB4, rem = i - fb * PB4;
  const float4* p = (const float4*)Gxp;
  float4 s = p[(size_t)fb * KS_G * PB4 + rem];
#pragma unroll
  for (int k = 1; k < KS_G; ++k) {
    float4 v = p[((size_t)fb * KS_G + k) * PB4 + rem];
    s.x += v.x; s.y += v.y; s.z += v.z; s.w += v.w;
  }
  ((float4*)Gx)[i] = s;
}

// ---------------------------------------------------------------------------
// k_mid1: T2 = W[0:512] @ G_b (B staged from f32 Gx, cast inline) -> bf16 T2b,
// plus fused ssq[row] += sum_col W[row,col]*T2[row,col] (f32 atomics).
__global__ __launch_bounds__(256) void k_mid1(const ushort_t* __restrict__ wqb,
                                              const float* __restrict__ Gx,
                                              ushort_t* __restrict__ T2b,
                                              float* __restrict__ ssq) {
  __shared__ __align__(16) short As[128 * 72];
  __shared__ __align__(16) short Bs[128 * 72];
  const int bm = blockIdx.x * 128;     // W rows 0..511
  const int b  = blockIdx.y >> 1;
  const int jb = blockIdx.y & 1;       // G col block
  const int t = threadIdx.x;
  const int oc = t & 7;
  const int rr = t >> 3;
  const int lane = t & 63, wave = t >> 6;
  const int m16 = lane & 15, quad = lane >> 4;
  const int wm = (wave >> 1) << 6, wn = (wave & 1) << 6;
  const float* Bsrc = Gx + ((size_t)b * GX_ROWS + jb * 128) * 256;
  floatx4 acc[4][4];
#pragma unroll
  for (int i = 0; i < 4; ++i)
#pragma unroll
    for (int j = 0; j < 4; ++j) acc[i][j] = (floatx4)(0.f);
#pragma unroll 1
  for (int k0 = 0; k0 < 256; k0 += 64) {
    short8 a8[4], b8[4];
#pragma unroll
    for (int j = 0; j < 4; ++j) {
      const int r = rr + 32 * j;
      a8[j] = *(const short8*)&wqb[(size_t)(bm + r) * 256 + k0 + 8 * oc];
      float4 g0 = *(const float4*)&Bsrc[(size_t)r * 256 + k0 + 8 * oc];
      float4 g1 = *(const float4*)&Bsrc[(size_t)r * 256 + k0 + 8 * oc + 4];
      short8 bb;
      bb[0] = f2bf(g0.x); bb[1] = f2bf(g0.y); bb[2] = f2bf(g0.z); bb[3] = f2bf(g0.w);
      bb[4] = f2bf(g1.x); bb[5] = f2bf(g1.y); bb[6] = f2bf(g1.z); bb[7] = f2bf(g1.w);
      b8[j] = bb;
    }
    __syncthreads();
#pragma unroll
    for (int j = 0; j < 4; ++j) {
      const int r = rr + 32 * j;
      *(short8*)&As[r * 72 + 8 * oc] = a8[j];
      *(short8*)&Bs[r * 72 + 8 * oc] = b8[j];
    }
    __syncthreads();
#pragma unroll
    for (int ks = 0; ks < 2; ++ks) {
      short8 af[4], bf[4];
#pragma unroll
      for (int i = 0; i < 4; ++i)
        af[i] = *(const short8*)&As[(wm + i * 16 + m16) * 72 + ks * 32 + quad * 8];
#pragma unroll
      for (int j = 0; j < 4; ++j)
        bf[j] = *(const short8*)&Bs[(wn + j * 16 + m16) * 72 + ks * 32 + quad * 8];
#pragma unroll
      for (int i = 0; i < 4; ++i)
#pragma unroll
        for (int j = 0; j < 4; ++j)
          acc[i][j] = __builtin_amdgcn_mfma_f32_16x16x32_bf16(af[i], bf[j], acc[i][j], 0, 0, 0);
    }
  }
#pragma unroll
  for (int i = 0; i < 4; ++i)
#pragma unroll
    for (int r = 0; r < 4; ++r) {
      const int gr = bm + wm + i * 16 + quad * 4 + r;  // 0..511
      float s = 0.f;
#pragma unroll
      for (int j = 0; j < 4; ++j) {
        const int col = jb * 128 + wn + j * 16 + m16;
        T2b[((size_t)b * 512 + gr) * 256 + col] = (ushort_t)f2bf(acc[i][j][r]);
        s += bf2f(wqb[(size_t)gr * 256 + col]) * acc[i][j][r];
      }
      s += __shfl_xor(s, 1);
      s += __shfl_xor(s, 2);
      s += __shfl_xor(s, 4);
      s += __shfl_xor(s, 8);
      if (m16 == 0) atomicAdd(&ssq[b * 512 + gr], s);
    }
}

// ---------------------------------------------------------------------------
// k_mid2: per-(b,h) small GEMMs. 256 threads/block: wave w owns output rows
// 16w..16w+15 (M-split; no cross-wave reduction). K=256.
__global__ __launch_bounds__(256) void k_mid2(const ushort_t* __restrict__ wqb,
                                              const ushort_t* __restrict__ T2b,
                                              const float* __restrict__ Gx,
                                              const float* __restrict__ ssq,
                                              const float* __restrict__ bE,
                                              const float* __restrict__ t1,
                                              const float* __restrict__ t2,
                                              ushort_t* __restrict__ ab,
                                              ushort_t* __restrict__ ksb,
                                              ushort_t* __restrict__ vsb) {
  const int bh = blockIdx.x;
  const int job = blockIdx.y;
  const int b = bh >> 2, h = bh & 3;
  const int wave = threadIdx.x >> 6;   // = output row-block (i)
  const int lane = threadIdx.x & 63;
  const int m16 = lane & 15, quad = lane >> 4;
  const int Abase = (job == 0 ? 0 : (job == 1 ? 256 : 768)) + h * 64;
  const int arow = Abase + 16 * wave + m16;
  floatx4 acc[4];
#pragma unroll
  for (int j = 0; j < 4; ++j) acc[j] = (floatx4)(0.f);
#pragma unroll
  for (int ks = 0; ks < 8; ++ks) {
    const int boct = ks * 32 + quad * 8;
    short8 af = *(const short8*)&wqb[(size_t)arow * 256 + boct];
    short8 bf[4];
    if (job == 0) {
#pragma unroll
      for (int j = 0; j < 4; ++j)
        bf[j] = *(const short8*)&T2b[((size_t)b * 512 + 256 + h * 64 + 16 * j + m16) * 256 + boct];
    } else {
#pragma unroll
      for (int j = 0; j < 4; ++j) {
        const float* gp = Gx + ((size_t)b * GX_ROWS + 256 + 16 * j + m16) * 256 + boct;
        float4 g0 = *(const float4*)gp;
        float4 g1 = *(const float4*)(gp + 4);
        short8 bb;
        bb[0] = f2bf(g0.x); bb[1] = f2bf(g0.y); bb[2] = f2bf(g0.z); bb[3] = f2bf(g0.w);
        bb[4] = f2bf(g1.x); bb[5] = f2bf(g1.y); bb[6] = f2bf(g1.z); bb[7] = f2bf(g1.w);
        bf[j] = bb;
      }
    }
#pragma unroll
    for (int j = 0; j < 4; ++j)
      acc[j] = __builtin_amdgcn_mfma_f32_16x16x32_bf16(af, bf[j], acc[j], 0, 0, 0);
  }
  if (job == 0) {
    const float t1h = t1[h];
    float rnk[4];
#pragma unroll
    for (int j = 0; j < 4; ++j)
      rnk[j] = 1.f / fmaxf(sqrtf(ssq[b * 512 + 256 + h * 64 + 16 * j + m16]), 1e-12f);
#pragma unroll
    for (int r = 0; r < 4; ++r) {
      const int d = 16 * wave + quad * 4 + r;
      const float rq = 1.f / fmaxf(sqrtf(ssq[b * 512 + h * 64 + d]), 1e-12f);
      float l[4];
      float m = -1e30f;
#pragma unroll
      for (int j = 0; j < 4; ++j) {
        l[j] = acc[j][r] * rq * rnk[j] * t1h;
        m = fmaxf(m, l[j]);
      }
      m = fmaxf(m, __shfl_xor(m, 1));
      m = fmaxf(m, __shfl_xor(m, 2));
      m = fmaxf(m, __shfl_xor(m, 4));
      m = fmaxf(m, __shfl_xor(m, 8));
      float s = 0.f;
#pragma unroll
      for (int j = 0; j < 4; ++j) {
        l[j] = __expf(l[j] - m);
        s += l[j];
      }
      s += __shfl_xor(s, 1);
      s += __shfl_xor(s, 2);
      s += __shfl_xor(s, 4);
      s += __shfl_xor(s, 8);
      const float inv = 1.f / s;
#pragma unroll
      for (int j = 0; j < 4; ++j)
        ab[(size_t)bh * 4096 + d * 64 + 16 * j + m16] = (ushort_t)f2bf(l[j] * inv);
    }
  } else if (job == 1) {
    const float tt = t2[h];
#pragma unroll
    for (int r = 0; r < 4; ++r) {
      const int d = 16 * wave + quad * 4 + r;
      const float rq = 1.f / fmaxf(sqrtf(ssq[b * 512 + h * 64 + d]), 1e-12f);
#pragma unroll
      for (int j = 0; j < 4; ++j) {
        const int p = 16 * j + m16;
        ksb[(size_t)bh * 4096 + p * 64 + d] =
            (ushort_t)f2bf((acc[j][r] + bE[p]) * rq * tt);
      }
    }
  } else {
#pragma unroll
    for (int r = 0; r < 4; ++r) {
      const int d = 16 * wave + quad * 4 + r;
#pragma unroll
      for (int j = 0; j < 4; ++j) {
        const int p = 16 * j + m16;
        vsb[(size_t)bh * 4096 + d * 64 + p] = (ushort_t)f2bf(acc[j][r] + bE[p]);
      }
    }
  }
}

// ---------------------------------------------------------------------------
// k_tok: fused qv-projection + both attentions + out-projection.
// One block = 64 tokens, wave w = head w. TWO LDS buffers (66 KB -> 2 blk/CU):
//   Ys: q -> P -> x_sa   (wave-private column strips)
//   Xs: x -> [barrier] -> v_ca -> x_ca
__global__ __launch_bounds__(256, 2) void k_tok(const float* __restrict__ x,
                                                const ushort_t* __restrict__ wqb,
                                                const ushort_t* __restrict__ ab,
                                                const ushort_t* __restrict__ ksb,
                                                const ushort_t* __restrict__ vsb,
                                                const ushort_t* __restrict__ w1b,
                                                const float* __restrict__ b1,
                                                const ushort_t* __restrict__ w2b,
                                                const float* __restrict__ b2,
                                                const float* __restrict__ pa,
                                                float* __restrict__ out) {
  __shared__ __align__(16) short Xs[64 * 264];
  __shared__ __align__(16) short Ys[64 * 264];
  const int n0 = blockIdx.x * 64;
  const int b = n0 >> 12;
  const int t = threadIdx.x;
  const int lane = t & 63, wave = t >> 6;
  const int m16 = lane & 15, quad = lane >> 4;
  const int cw = wave * 64;            // this wave's column strip / head base
  const int bh = b * 4 + wave;
  // ---- phase 1: stage x tile (f32 -> bf16)
#pragma unroll
  for (int rep = 0; rep < 16; ++rep) {
    const int f4 = rep * 256 + t;
    const int row = f4 >> 6, c4 = f4 & 63;
    float4 v = *(const float4*)&x[(size_t)(n0 + row) * 256 + c4 * 4];
    *(short4v*)&Xs[row * 264 + c4 * 4] = cvt4(v);
  }
  __syncthreads();
  // ---- phase 2a: q = x @ Wq_h^T -> Ys strip
  {
    floatx4 acc[4][4];
#pragma unroll
    for (int i = 0; i < 4; ++i)
#pragma unroll
      for (int j = 0; j < 4; ++j) acc[i][j] = (floatx4)(0.f);
#pragma unroll
    for (int ks = 0; ks < 8; ++ks) {
      const int boct = ks * 32 + quad * 8;
      short8 af[4], bf[4];
#pragma unroll
      for (int i = 0; i < 4; ++i)
        af[i] = *(const short8*)&Xs[(16 * i + m16) * 264 + boct];
#pragma unroll
      for (int j = 0; j < 4; ++j)
        bf[j] = *(const short8*)&wqb[(size_t)(cw + 16 * j + m16) * 256 + boct];
#pragma unroll
      for (int i = 0; i < 4; ++i)
#pragma unroll
        for (int j = 0; j < 4; ++j)
          acc[i][j] = __builtin_amdgcn_mfma_f32_16x16x32_bf16(af[i], bf[j], acc[i][j], 0, 0, 0);
    }
#pragma unroll
    for (int i = 0; i < 4; ++i)
#pragma unroll
      for (int r = 0; r < 4; ++r)
#pragma unroll
        for (int j = 0; j < 4; ++j)
          Ys[(16 * i + quad * 4 + r) * 264 + cw + 16 * j + m16] =
              (short)f2bf(acc[i][j][r]);
  }
  // ---- phase 3: spatial attention for head = wave (all within own Ys strip)
  {
    floatx4 s[4][4];
#pragma unroll
    for (int i = 0; i < 4; ++i)
#pragma unroll
      for (int j = 0; j < 4; ++j) s[i][j] = (floatx4)(0.f);
#pragma unroll
    for (int ks = 0; ks < 2; ++ks) {
      const int boct = ks * 32 + quad * 8;
      short8 af[4], bf[4];
#pragma unroll
      for (int i = 0; i < 4; ++i)
        af[i] = *(const short8*)&Ys[(16 * i + m16) * 264 + cw + boct];
#pragma unroll
      for (int j = 0; j < 4; ++j)
        bf[j] = *(const short8*)&ksb[(size_t)bh * 4096 + (16 * j + m16) * 64 + boct];
#pragma unroll
      for (int i = 0; i < 4; ++i)
#pragma unroll
        for (int j = 0; j < 4; ++j)
          s[i][j] = __builtin_amdgcn_mfma_f32_16x16x32_bf16(af[i], bf[j], s[i][j], 0, 0, 0);
    }
    // softmax per token-row (64 wide: 4 j-blocks x 16 lanes)
#pragma unroll
    for (int i = 0; i < 4; ++i)
#pragma unroll
      for (int r = 0; r < 4; ++r) {
        float mr = fmaxf(fmaxf(s[i][0][r], s[i][1][r]), fmaxf(s[i][2][r], s[i][3][r]));
        mr = fmaxf(mr, __shfl_xor(mr, 1));
        mr = fmaxf(mr, __shfl_xor(mr, 2));
        mr = fmaxf(mr, __shfl_xor(mr, 4));
        mr = fmaxf(mr, __shfl_xor(mr, 8));
        float sr = 0.f;
#pragma unroll
        for (int j = 0; j < 4; ++j) {
          const float e = __expf(s[i][j][r] - mr);
          s[i][j][r] = e;
          sr += e;
        }
        sr += __shfl_xor(sr, 1);
        sr += __shfl_xor(sr, 2);
        sr += __shfl_xor(sr, 4);
        sr += __shfl_xor(sr, 8);
        const float inv = 1.f / sr;
#pragma unroll
        for (int j = 0; j < 4; ++j) s[i][j][r] *= inv;
      }
    // P -> Ys strip (overwrites q; ordered after q reads by data dependence)
#pragma unroll
    for (int i = 0; i < 4; ++i)
#pragma unroll
      for (int r = 0; r < 4; ++r)
#pragma unroll
        for (int j = 0; j < 4; ++j)
          Ys[(16 * i + quad * 4 + r) * 264 + cw + 16 * j + m16] =
              (short)f2bf(s[i][j][r]);
    // PV: x_sa = P @ vsb^T(d rows)
    floatx4 o[4][4];
#pragma unroll
    for (int i = 0; i < 4; ++i)
#pragma unroll
      for (int j = 0; j < 4; ++j) o[i][j] = (floatx4)(0.f);
#pragma unroll
    for (int ks = 0; ks < 2; ++ks) {
      const int boct = ks * 32 + quad * 8;
      short8 af[4], bf[4];
#pragma unroll
      for (int i = 0; i < 4; ++i)
        af[i] = *(const short8*)&Ys[(16 * i + m16) * 264 + cw + boct];
#pragma unroll
      for (int j = 0; j < 4; ++j)
        bf[j] = *(const short8*)&vsb[(size_t)bh * 4096 + (16 * j + m16) * 64 + boct];
#pragma unroll
      for (int i = 0; i < 4; ++i)
#pragma unroll
        for (int j = 0; j < 4; ++j)
          o[i][j] = __builtin_amdgcn_mfma_f32_16x16x32_bf16(af[i], bf[j], o[i][j], 0, 0, 0);
    }
    // x_sa -> Ys strip
#pragma unroll
    for (int i = 0; i < 4; ++i)
#pragma unroll
      for (int r = 0; r < 4; ++r)
#pragma unroll
        for (int j = 0; j < 4; ++j)
          Ys[(16 * i + quad * 4 + r) * 264 + cw + 16 * j + m16] =
              (short)f2bf(o[i][j][r]);
  }
  // ---- phase 2b: v_ca = x @ Wv2_h^T, accumulate in regs (last reader of Xs)
  floatx4 accv[4][4];
#pragma unroll
  for (int i = 0; i < 4; ++i)
#pragma unroll
    for (int j = 0; j < 4; ++j) accv[i][j] = (floatx4)(0.f);
#pragma unroll
  for (int ks = 0; ks < 8; ++ks) {
    const int boct = ks * 32 + quad * 8;
    short8 af[4], bf[4];
#pragma unroll
    for (int i = 0; i < 4; ++i)
      af[i] = *(const short8*)&Xs[(16 * i + m16) * 264 + boct];
#pragma unroll
    for (int j = 0; j < 4; ++j)
      bf[j] = *(const short8*)&wqb[(size_t)(512 + cw + 16 * j + m16) * 256 + boct];
#pragma unroll
    for (int i = 0; i < 4; ++i)
#pragma unroll
      for (int j = 0; j < 4; ++j)
        accv[i][j] = __builtin_amdgcn_mfma_f32_16x16x32_bf16(af[i], bf[j], accv[i][j], 0, 0, 0);
  }
  __syncthreads();   // all waves done reading x from Xs
  // v_ca -> Xs strip
#pragma unroll
  for (int i = 0; i < 4; ++i)
#pragma unroll
    for (int r = 0; r < 4; ++r)
#pragma unroll
      for (int j = 0; j < 4; ++j)
        Xs[(16 * i + quad * 4 + r) * 264 + cw + 16 * j + m16] =
            (short)f2bf(accv[i][j][r]);
  // ---- phase 4: channel attention x_ca = v_ca @ ab^T (own strip only)
  {
    floatx4 o[4][4];
#pragma unroll
    for (int i = 0; i < 4; ++i)
#pragma unroll
      for (int j = 0; j < 4; ++j) o[i][j] = (floatx4)(0.f);
#pragma unroll
    for (int ks = 0; ks < 2; ++ks) {
      const int boct = ks * 32 + quad * 8;
      short8 af[4], bf[4];
#pragma unroll
      for (int i = 0; i < 4; ++i)
        af[i] = *(const short8*)&Xs[(16 * i + m16) * 264 + cw + boct];
#pragma unroll
      for (int j = 0; j < 4; ++j)
        bf[j] = *(const short8*)&ab[(size_t)bh * 4096 + (16 * j + m16) * 64 + boct];
#pragma unroll
      for (int i = 0; i < 4; ++i)
#pragma unroll
        for (int j = 0; j < 4; ++j)
          o[i][j] = __builtin_amdgcn_mfma_f32_16x16x32_bf16(af[i], bf[j], o[i][j], 0, 0, 0);
    }
#pragma unroll
    for (int i = 0; i < 4; ++i)
#pragma unroll
      for (int r = 0; r < 4; ++r)
#pragma unroll
        for (int j = 0; j < 4; ++j)
          Xs[(16 * i + quad * 4 + r) * 264 + cw + 16 * j + m16] =
              (short)f2bf(o[i][j][r]);
  }
  __syncthreads();   // Ys = x_sa, Xs = x_ca complete across waves
  // ---- phase 5: out = PReLU([x_sa@W1^T ; x_ca@W2^T] + bias)
  {
    const short* Asrc = (wave < 2) ? Ys : Xs;
    const ushort_t* Wsrc = (wave < 2) ? w1b : w2b;
    const float* bias = (wave < 2) ? b1 : b2;
    const int wrow = (wave & 1) * 64;
    const int colbase = (wave < 2 ? 0 : 128) + wrow;
    floatx4 acc[4][4];
#pragma unroll
    for (int i = 0; i < 4; ++i)
#pragma unroll
      for (int j = 0; j < 4; ++j) acc[i][j] = (floatx4)(0.f);
#pragma unroll
    for (int ks = 0; ks < 8; ++ks) {
      const int boct = ks * 32 + quad * 8;
      short8 af[4], bf[4];
#pragma unroll
      for (int i = 0; i < 4; ++i)
        af[i] = *(const short8*)&Asrc[(16 * i + m16) * 264 + boct];
#pragma unroll
      for (int j = 0; j < 4; ++j)
        bf[j] = *(const short8*)&Wsrc[(size_t)(wrow + 16 * j + m16) * 256 + boct];
#pragma unroll
      for (int i = 0; i < 4; ++i)
#pragma unroll
        for (int j = 0; j < 4; ++j)
          acc[i][j] = __builtin_amdgcn_mfma_f32_16x16x32_bf16(af[i], bf[j], acc[i][j], 0, 0, 0);
    }
    const float slope = pa[0];
    float bj[4];
#pragma unroll
    for (int j = 0; j < 4; ++j) bj[j] = bias[wrow + 16 * j + m16];
#pragma unroll
    for (int i = 0; i < 4; ++i)
#pragma unroll
      for (int r = 0; r < 4; ++r) {
        const int gr = n0 + 16 * i + quad * 4 + r;
#pragma unroll
        for (int j = 0; j < 4; ++j) {
          float v = acc[i][j][r] + bj[j];
          v = v >= 0.f ? v : slope * v;
          out[(size_t)gr * C_ + colbase + 16 * j + m16] = v;
        }
      }
  }
}

// ---------------------------------------------------------------------------
extern "C" void kernel_launch(void* const* d_in, const int* in_sizes, int n_in,
                              void* d_out, int out_size, void* d_ws, size_t ws_size,
                              hipStream_t stream) {
  (void)in_sizes; (void)n_in; (void)out_size; (void)ws_size;
  const float* x  = (const float*)d_in[0];
  // d_in[1] = bank (unused by forward)
  const float* Wq = (const float*)d_in[2];
  const float* WE = (const float*)d_in[3];
  const float* bE = (const float*)d_in[4];
  const float* t1 = (const float*)d_in[5];
  const float* t2 = (const float*)d_in[6];
  const float* W1 = (const float*)d_in[7];
  const float* b1 = (const float*)d_in[8];
  const float* W2 = (const float*)d_in[9];
  const float* b2 = (const float*)d_in[10];
  const float* pa = (const float*)d_in[11];
  float* out = (float*)d_out;

  float* ws = (float*)d_ws;
  size_t off = 0;
  float* Gx  = ws + off; off += (size_t)B_ * GX_ROWS * 256;          //   655,360
  float* ssq = ws + off; off += (size_t)B_ * 512;                    //     4,096
  float* Gxp = ws + off; off += (size_t)KS_G * B_ * GX_ROWS * 256;   // 5,242,880
  ushort_t* ksb = (ushort_t*)(ws + off); off += 32 * 4096 / 2;  // bf16 [bh][p][d]
  ushort_t* vsb = (ushort_t*)(ws + off); off += 32 * 4096 / 2;  // bf16 [bh][d][p]
  ushort_t* ab  = (ushort_t*)(ws + off); off += 32 * 4096 / 2;  // bf16 attn
  ushort_t* xt  = (ushort_t*)(ws + off); off += (size_t)M_ * C_ / 2;   // bf16 x^T
  ushort_t* wqb = (ushort_t*)(ws + off); off += (size_t)OC_ * C_ / 2;  // bf16 Wq
  ushort_t* w1b = (ushort_t*)(ws + off); off += (size_t)128 * C_ / 2;
  ushort_t* w2b = (ushort_t*)(ws + off); off += (size_t)128 * C_ / 2;
  ushort_t* web = (ushort_t*)(ws + off); off += (size_t)P_ * N_ / 2;   // bf16 WE
  ushort_t* T2b = (ushort_t*)(ws + off); off += (size_t)B_ * 512 * C_ / 2;

  k_cast<<<XT_TILES + 128, 256, 0, stream>>>(x, Wq, WE, W1, W2,
                                             xt, wqb, web, w1b, w2b, ssq);
  k_gram<<<dim3(3, B_ * KS_G), 512, 0, stream>>>(xt, web, Gxp);
  k_gred<<<GX_ROWS * 256 * B_ / 4 / 256, 256, 0, stream>>>(Gxp, Gx);
  k_mid1<<<dim3(4, B_ * 2), 256, 0, stream>>>(wqb, Gx, T2b, ssq);
  k_mid2<<<dim3(32, 3), 256, 0, stream>>>(wqb, T2b, Gx, ssq, bE, t1, t2, ab, ksb, vsb);
  k_tok<<<M_ / 64, 256, 0, stream>>>(x, wqb, ab, ksb, vsb, w1b, b1, w2b, b2, pa, out);
}